// Round 1
// baseline (337.934 us; speedup 1.0000x reference)
//
#include <hip/hip_runtime.h>

// LiftSplatShoot with identity camera params.
// Key static facts (derived from the reference's _precompute):
//  - Only depth bins k=0..11 (d = 4.0..9.5) give iz==0 (z=d, iz=trunc((d+10)/20)).
//  - x,y always within [-9.5,9.5] => ix,iy always in [0,200). So exactly
//    12*24*40 = 11520 kept points.
//  - out[b=0, c, ix, iy] = sum over kept (k,h,w) mapping to (ix,iy) of
//    depth[k,h,w] * feat[c,h,w].
//  - Along one ray (h,w), x and y are monotone in d, so equal-voxel points
//    form contiguous runs: merging consecutive equal voxels fully dedups
//    the per-ray entry list.

#define NX0 200
#define NX1 200
#define NC 512
#define FH 24
#define FW 40
#define NRAY (FH * FW)
#define ND 12        // depth bins that land in iz==0

__global__ __launch_bounds__(512)
void lss_scatter(const float* __restrict__ feat,
                 const float* __restrict__ depth,
                 float* __restrict__ out) {
#pragma clang fp contract(off)
    __shared__ int   s_vox[ND];
    __shared__ float s_dep[ND];
    __shared__ int   s_evox[ND];
    __shared__ float s_ew[ND];
    __shared__ int   s_ne;

    const int ray = blockIdx.x;          // ray = h*FW + w
    const int w   = ray % FW;
    const int h   = ray / FW;
    const int tid = threadIdx.x;

    if (tid < ND) {
        // Replicate numpy float64 math bit-exactly (fp contract off).
        // xs = linspace(0,639,40): xs[k] = fl(k * fl(639/39)), xs[39]=639 exact.
        // ys = linspace(0,383,24): ys[j] = fl(j * fl(383/23)), ys[23]=383 exact.
        const double a = 1.0 / 320.0;                    // inv(K)[0][0] == inv(K)[1][1]
        double u = (w == FW - 1) ? 639.0 : (double)w * (639.0 / 39.0);
        double v = (h == FH - 1) ? 383.0 : (double)h * (383.0 / 23.0);
        double d = 4.0 + 0.5 * (double)tid;              // arange(4,44,0.5), exact

        double xc = u * d;                               // f[...,0]*f[...,2]
        double yc = v * d;
        // pts @ inv(K).T with inv(K) = [[a,0,-1],[0,a,-0.5625],[0,0,1]]
        double x = (xc * a) - d;                         // middle term is +0
        double y = (yc * a) - 0.5625 * d;                // 0.5625*d exact (dyadic)
        // ((pts - (bx - dx/2)) / dx); bx-dx/2 = (-50,-50,-10), dx=(0.5,0.5,20)
        double gx = (x + 50.0) * 2.0;                    // /0.5 exact
        double gy = (y + 50.0) * 2.0;
        double gz = (d + 10.0) / 20.0;

        int ix = (int)gx;    // C cast truncates toward zero == np.trunc->int64
        int iy = (int)gy;
        int iz = (int)gz;
        bool keep = (ix >= 0) && (ix < NX0) &&
                    (iy >= 0) && (iy < NX1) &&
                    (iz == 0);
        s_vox[tid] = keep ? (ix * NX1 + iy) : -1;
        s_dep[tid] = depth[tid * NRAY + ray];
    }
    __syncthreads();

    if (tid == 0) {
        // merge contiguous equal-voxel runs along depth
        int ne = 0;
        int prev = -2;
        for (int k = 0; k < ND; ++k) {
            int vx = s_vox[k];
            if (vx < 0) { prev = -2; continue; }
            if (vx == prev) {
                s_ew[ne - 1] += s_dep[k];
            } else {
                s_evox[ne] = vx;
                s_ew[ne]   = s_dep[k];
                prev = vx;
                ++ne;
            }
        }
        s_ne = ne;
    }
    __syncthreads();

    const int ne = s_ne;
    const int c  = tid;                       // 512 threads == 512 channels
    const float f = feat[c * NRAY + ray];
    float* outc = out + (size_t)c * (NX0 * NX1);
    for (int e = 0; e < ne; ++e) {
        atomicAdd(&outc[s_evox[e]], s_ew[e] * f);
    }
}

extern "C" void kernel_launch(void* const* d_in, const int* in_sizes, int n_in,
                              void* d_out, int out_size, void* d_ws, size_t ws_size,
                              hipStream_t stream) {
    const float* feat  = (const float*)d_in[0];   // (1, 512, 24, 40)
    const float* depth = (const float*)d_in[1];   // (1, 80, 24, 40)
    float* out = (float*)d_out;                   // (1, 512, 200, 200)

    // d_out is poisoned before every timed launch; zero it (most voxels empty).
    hipMemsetAsync(out, 0, (size_t)out_size * sizeof(float), stream);

    lss_scatter<<<NRAY, 512, 0, stream>>>(feat, depth, out);
}

// Round 2
// 175.697 us; speedup vs baseline: 1.9234x; 1.9234x over previous
//
#include <hip/hip_runtime.h>

// LiftSplatShoot, identity camera. Static facts (see round-0/1 analysis):
//  - Only depth bins k=0..11 (d=4.0..9.5) survive (iz==0).
//  - All kept points land in ix in [81,118], iy in [89,112].
//  - Along a ray, x and y are monotone in d => each (ray,voxel) pair is one
//    contiguous depth-run => after run-merge, <=1 entry per (ray,voxel).
//  - out[c,ix,iy] = sum over entries of weight * feat[c,ray].
// Strategy: per-launch build inverse (voxel -> list of (weight,ray)) in device
// globals, then a pure-gather kernel writes the whole 82MB output (zeros for
// inactive voxels) with coalesced float4 stores. No fp32 atomics, no memset.

#define NX0 200
#define NX1 200
#define NC 512
#define FH 24
#define FW 40
#define NRAY (FH * FW)
#define ND 12          // depth bins with iz==0
#define BX0 80         // active bbox with margin
#define BNX 40         // ix in [80,120)
#define BY0 88
#define BNY 26         // iy in [88,114)
#define NVB (BNX * BNY)
#define CAP 64         // max (ray,run) entries per voxel (est. worst ~30)

struct Entry { float w; int ray; };

__device__ int   g_cnt[NVB];
__device__ Entry g_ent[NVB * CAP];

__global__ __launch_bounds__(1024)
void lss_build(const float* __restrict__ depth) {
#pragma clang fp contract(off)
    const int tid = threadIdx.x;
    for (int i = tid; i < NVB; i += 1024) g_cnt[i] = 0;
    __syncthreads();
    if (tid >= NRAY) return;

    const int ray = tid;
    const int w = ray % FW;
    const int h = ray / FW;

    // numpy float64 math, bit-exact (contract off, same op order as reference)
    const double a = 1.0 / 320.0;
    double u = (w == FW - 1) ? 639.0 : (double)w * (639.0 / 39.0);
    double v = (h == FH - 1) ? 383.0 : (double)h * (383.0 / 23.0);

    int   prev = -2;
    float wsum = 0.0f;
    for (int k = 0; k < ND; ++k) {
        double d  = 4.0 + 0.5 * (double)k;
        double x  = (u * d) * a - d;
        double y  = (v * d) * a - 0.5625 * d;
        double gx = (x + 50.0) * 2.0;
        double gy = (y + 50.0) * 2.0;
        int ix = (int)gx;
        int iy = (int)gy;
        int lv = -1;
        if (ix >= 0 && ix < NX0 && iy >= 0 && iy < NX1)
            lv = (ix - BX0) * BNY + (iy - BY0);
        float dv = depth[k * NRAY + ray];
        if (lv == prev) {
            wsum += dv;
        } else {
            if (prev >= 0) {
                int slot = atomicAdd(&g_cnt[prev], 1);
                if (slot < CAP) g_ent[prev * CAP + slot] = { wsum, ray };
            }
            prev = lv;
            wsum = dv;
        }
    }
    if (prev >= 0) {
        int slot = atomicAdd(&g_cnt[prev], 1);
        if (slot < CAP) g_ent[prev * CAP + slot] = { wsum, ray };
    }
}

// Each thread produces 4 consecutive output elements (one float4 store).
// out layout: (c, ix, iy) with iy fastest; 40000 % 4 == 0 so the 4 elements
// never cross a channel boundary.
__global__ __launch_bounds__(256)
void lss_gather(const float* __restrict__ feat, float* __restrict__ out) {
    const int t    = blockIdx.x * 256 + threadIdx.x;
    const int base = t * 4;                  // < 512*40000 = 20.48M, fits int
    const int c    = base / (NX0 * NX1);
    const int vox0 = base - c * (NX0 * NX1);
    const float* fc = feat + c * NRAY;

    float r[4];
#pragma unroll
    for (int j = 0; j < 4; ++j) {
        const int v  = vox0 + j;
        const int ix = v / NX1;
        const int iy = v - ix * NX1;
        float s = 0.0f;
        if ((unsigned)(ix - BX0) < BNX && (unsigned)(iy - BY0) < BNY) {
            const int lv = (ix - BX0) * BNY + (iy - BY0);
            int n = g_cnt[lv];
            if (n > CAP) n = CAP;
            const Entry* e = &g_ent[lv * CAP];
            for (int i = 0; i < n; ++i)
                s += e[i].w * fc[e[i].ray];
        }
        r[j] = s;
    }
    *(float4*)(out + base) = make_float4(r[0], r[1], r[2], r[3]);
}

extern "C" void kernel_launch(void* const* d_in, const int* in_sizes, int n_in,
                              void* d_out, int out_size, void* d_ws, size_t ws_size,
                              hipStream_t stream) {
    const float* feat  = (const float*)d_in[0];   // (1, 512, 24, 40)
    const float* depth = (const float*)d_in[1];   // (1, 80, 24, 40)
    float* out = (float*)d_out;                   // (1, 512, 200, 200)

    lss_build<<<1, 1024, 0, stream>>>(depth);

    const int total = NC * NX0 * NX1;             // 20,480,000
    lss_gather<<<total / 4 / 256, 256, 0, stream>>>(feat, out);
}